// Round 3
// baseline (163.994 us; speedup 1.0000x reference)
//
#include <hip/hip_runtime.h>

// Problem constants: B=128, P=2048, N=256, D=2
constexpr int B     = 128;
constexpr int P     = 2048;
constexpr int N     = 256;
constexpr int TPB   = 256;      // 4 waves
constexpr int CPW   = 8;        // centers per wave
constexpr int NPB   = 32;       // centers per block = 4 waves * 8
constexpr int PPL   = P / 64;   // 32 points per lane (full row resident)
constexpr int PAIRS = PPL / 2;  // 16

__device__ __forceinline__ float rdfl(float v) {
    return __int_as_float(__builtin_amdgcn_readfirstlane(__float_as_int(v)));
}

__global__ __launch_bounds__(TPB, 4)   // 128-VGPR budget: room to keep row in regs
void SLayerRational_43190191128606_kernel(
    const float* __restrict__ batch,      // (B, P, 2)
    const float* __restrict__ not_dummy,  // (B, P)
    const float* __restrict__ centers,    // (N, 2)
    const float* __restrict__ sharpness,  // (N, 2)
    const float* __restrict__ exponent,   // (1,)
    float* __restrict__ out)              // (B, N)
{
    const int b    = blockIdx.x >> 3;          // N/NPB = 8 tiles per batch row
    const int n0   = (blockIdx.x & 7) * NPB;
    const int wave = threadIdx.x >> 6;
    const int lane = threadIdx.x & 63;
    const int nw   = n0 + wave * CPW;

    // Wave-uniform center params -> SGPRs
    float c0[CPW], c1[CPW], a0[CPW], a1[CPW];
#pragma unroll
    for (int c = 0; c < CPW; ++c) {
        c0[c] = rdfl(centers[(nw + c) * 2 + 0]);
        c1[c] = rdfl(centers[(nw + c) * 2 + 1]);
        a0[c] = rdfl(fabsf(sharpness[(nw + c) * 2 + 0]));
        a1[c] = rdfl(fabsf(sharpness[(nw + c) * 2 + 1]));
    }
    const float e = exponent[0];

    const float2* bb = reinterpret_cast<const float2*>(batch) + (size_t)b * P;
    const float*  nd = not_dummy + (size_t)b * P;

    // One-shot: pull this lane's 32 points into registers.
    float2 xp[PPL];
    float  wp[PPL];
#pragma unroll
    for (int k = 0; k < PPL; ++k) {
        const int p = k * 64 + lane;
        xp[k] = bb[p];
        wp[k] = nd[p];
    }

    float acc[CPW];
#pragma unroll
    for (int c = 0; c < CPW; ++c) acc[c] = 0.0f;

    if (e == 1.0f) {
        // Steady state: pure register VALU, zero memory ops.
        //   1/ua + 1/ub  ->  (wa*ub + wb*ua) / (ua*ub),  u = 1 + |d0|a0 + |d1|a1
#pragma unroll
        for (int c = 0; c < CPW; ++c) {
#pragma unroll
            for (int k = 0; k < PAIRS; ++k) {
                const float2 xa = xp[2 * k];
                const float2 xb = xp[2 * k + 1];
                const float ua = fmaf(fabsf(c0[c] - xa.x), a0[c],
                                  fmaf(fabsf(c1[c] - xa.y), a1[c], 1.0f));
                const float ub = fmaf(fabsf(c0[c] - xb.x), a0[c],
                                  fmaf(fabsf(c1[c] - xb.y), a1[c], 1.0f));
                float num = wp[2 * k] * ub;
                num = fmaf(wp[2 * k + 1], ua, num);
                const float den = ua * ub;
                acc[c] = fmaf(num, __builtin_amdgcn_rcpf(den), acc[c]);
            }
        }
    } else {
        // General path: r = w / (1 + s^e)
#pragma unroll
        for (int c = 0; c < CPW; ++c) {
            for (int k = 0; k < PPL; ++k) {
                const float s = fmaf(fabsf(c0[c] - xp[k].x), a0[c],
                                     fabsf(c1[c] - xp[k].y) * a1[c]);
                acc[c] += wp[k] / (1.0f + powf(s, e));
            }
        }
    }

    // Wave-local tree reduction; chains across centers are independent.
#pragma unroll
    for (int c = 0; c < CPW; ++c) {
#pragma unroll
        for (int off = 32; off > 0; off >>= 1)
            acc[c] += __shfl_down(acc[c], off, 64);
    }

    if (lane == 0) {
#pragma unroll
        for (int c = 0; c < CPW; ++c)
            out[b * N + nw + c] = acc[c];
    }
}

extern "C" void kernel_launch(void* const* d_in, const int* in_sizes, int n_in,
                              void* d_out, int out_size, void* d_ws, size_t ws_size,
                              hipStream_t stream) {
    const float* batch     = (const float*)d_in[0];
    const float* not_dummy = (const float*)d_in[1];
    const float* centers   = (const float*)d_in[2];
    const float* sharpness = (const float*)d_in[3];
    const float* exponent  = (const float*)d_in[4];
    float* out = (float*)d_out;

    const int blocks = B * (N / NPB);  // 1024
    SLayerRational_43190191128606_kernel<<<blocks, TPB, 0, stream>>>(
        batch, not_dummy, centers, sharpness, exponent, out);
}

// Round 4
// 19.578 us; speedup vs baseline: 8.3766x; 8.3766x over previous
//
#include <hip/hip_runtime.h>

// Problem constants: B=128, P=2048, N=256, D=2
constexpr int B   = 128;
constexpr int P   = 2048;
constexpr int N   = 256;
constexpr int TPB = 256;     // 4 waves
constexpr int CPW = 8;       // centers per wave
constexpr int NPB = 32;      // centers per block = 4 waves * 8
constexpr int HV  = 16;      // float4 loads per lane (2 points each -> 32 pts/lane)

__device__ __forceinline__ float rdfl(float v) {
    return __int_as_float(__builtin_amdgcn_readfirstlane(__float_as_int(v)));
}

__global__ __launch_bounds__(TPB, 4)   // 128-VGPR budget
void SLayerRational_43190191128606_kernel(
    const float* __restrict__ batch,      // (B, P, 2)
    const float* __restrict__ not_dummy,  // (B, P)
    const float* __restrict__ centers,    // (N, 2)
    const float* __restrict__ sharpness,  // (N, 2)
    const float* __restrict__ exponent,   // (1,)
    float* __restrict__ out)              // (B, N)
{
    const int b    = blockIdx.x >> 3;          // N/NPB = 8 tiles per batch row
    const int n0   = (blockIdx.x & 7) * NPB;
    const int wave = threadIdx.x >> 6;
    const int lane = threadIdx.x & 63;
    const int nw   = n0 + wave * CPW;

    // Wave-uniform center params -> SGPRs
    float c0[CPW], c1[CPW], a0[CPW], a1[CPW];
#pragma unroll
    for (int c = 0; c < CPW; ++c) {
        c0[c] = rdfl(centers[(nw + c) * 2 + 0]);
        c1[c] = rdfl(centers[(nw + c) * 2 + 1]);
        a0[c] = rdfl(fabsf(sharpness[(nw + c) * 2 + 0]));
        a1[c] = rdfl(fabsf(sharpness[(nw + c) * 2 + 1]));
    }
    const float e = exponent[0];

    float acc[CPW];
#pragma unroll
    for (int c = 0; c < CPW; ++c) acc[c] = 0.0f;

    if (e == 1.0f) {
        // ---- Fast path: row register-resident, ALL indices compile-time ----
        // Lane loads 16 float4 (= 32 points' xy) + 16 float2 (= 32 weights).
        const float4* bb4 = reinterpret_cast<const float4*>(batch) + (size_t)b * (P / 2);
        const float2* nd2 = reinterpret_cast<const float2*>(not_dummy) + (size_t)b * (P / 2);

        float4 xq[HV];
        float2 wq[HV];
#pragma unroll
        for (int k = 0; k < HV; ++k) {
            xq[k] = bb4[k * 64 + lane];
            wq[k] = nd2[k * 64 + lane];
        }

        // Steady state: pure register VALU. 12 instrs per 2 points per center.
#pragma unroll
        for (int c = 0; c < CPW; ++c) {
#pragma unroll
            for (int k = 0; k < HV; ++k) {
                const float4 x = xq[k];
                const float2 w = wq[k];
                const float ua = fmaf(fabsf(c0[c] - x.x), a0[c],
                                  fmaf(fabsf(c1[c] - x.y), a1[c], 1.0f));
                acc[c] = fmaf(w.x, __builtin_amdgcn_rcpf(ua), acc[c]);
                const float ub = fmaf(fabsf(c0[c] - x.z), a0[c],
                                  fmaf(fabsf(c1[c] - x.w), a1[c], 1.0f));
                acc[c] = fmaf(w.y, __builtin_amdgcn_rcpf(ub), acc[c]);
            }
        }
    } else {
        // ---- General path: r = w / (1 + s^e); direct global loads, no arrays ----
        const float2* bb = reinterpret_cast<const float2*>(batch) + (size_t)b * P;
        const float*  nd = not_dummy + (size_t)b * P;
        for (int it = 0; it < P / 64; ++it) {
            const int p = it * 64 + lane;
            const float2 x = bb[p];
            const float  w = nd[p];
#pragma unroll
            for (int c = 0; c < CPW; ++c) {
                const float s = fmaf(fabsf(c0[c] - x.x), a0[c],
                                     fabsf(c1[c] - x.y) * a1[c]);
                acc[c] += w / (1.0f + powf(s, e));
            }
        }
    }

    // Wave-local tree reduction; no LDS, no __syncthreads.
#pragma unroll
    for (int c = 0; c < CPW; ++c) {
#pragma unroll
        for (int off = 32; off > 0; off >>= 1)
            acc[c] += __shfl_down(acc[c], off, 64);
    }

    if (lane == 0) {
#pragma unroll
        for (int c = 0; c < CPW; ++c)
            out[b * N + nw + c] = acc[c];
    }
}

extern "C" void kernel_launch(void* const* d_in, const int* in_sizes, int n_in,
                              void* d_out, int out_size, void* d_ws, size_t ws_size,
                              hipStream_t stream) {
    const float* batch     = (const float*)d_in[0];
    const float* not_dummy = (const float*)d_in[1];
    const float* centers   = (const float*)d_in[2];
    const float* sharpness = (const float*)d_in[3];
    const float* exponent  = (const float*)d_in[4];
    float* out = (float*)d_out;

    const int blocks = B * (N / NPB);  // 1024
    SLayerRational_43190191128606_kernel<<<blocks, TPB, 0, stream>>>(
        batch, not_dummy, centers, sharpness, exponent, out);
}